// Round 21
// baseline (206.841 us; speedup 1.0000x reference)
//
#include <hip/hip_runtime.h>
#include <hip/hip_bf16.h>

#define DIM 2048
#define T_SEQ 2048
#define B_SZ 2
#define NH 16
#define NKV 4
#define HD 128
#define KVDIM (NKV * HD)            // 512
#define M_ROWS (B_SZ * T_SEQ)       // 4096
#define QKVN (DIM + 2 * KVDIM)      // 3072
#define QBLK 128
#define KVBLK 64

typedef float f32x4 __attribute__((ext_vector_type(4)));
typedef __bf16 bf16x8 __attribute__((ext_vector_type(8)));
typedef unsigned short u16x8 __attribute__((ext_vector_type(8)));

static __device__ __forceinline__ float bf2f(unsigned short u) {
    unsigned v = ((unsigned)u) << 16;
    return __builtin_bit_cast(float, v);
}
static __device__ __forceinline__ unsigned short f2bf(float f) {
    __bf16 h = (__bf16)f;
    return __builtin_bit_cast(unsigned short, h);
}

static __device__ __forceinline__ void gload16(const void* g, void* l) {
    __builtin_amdgcn_global_load_lds((const __attribute__((address_space(1))) void*)g,
                                     (__attribute__((address_space(3))) void*)l, 16, 0, 0);
}

// ---------------- elementwise f32 -> bf16, fused RoPE table build ----------------
__global__ void cvt_f32_bf16(const float* __restrict__ src, unsigned short* __restrict__ dst,
                             float2* __restrict__ tab, int n4) {
    int i = blockIdx.x * blockDim.x + threadIdx.x;
    if (blockIdx.x < 512) {  // also build tab[T_SEQ][64] (131072 entries)
        const int idx = blockIdx.x * 256 + threadIdx.x;
        const int tt = idx >> 6, ii = idx & 63;
        const float inv = exp2f(-(float)ii * (13.287712379549449f / 64.0f));  // 10000^(-i/64)
        const float ang = (float)tt * inv;
        tab[idx] = make_float2(cosf(ang), sinf(ang));
    }
    if (i >= n4) return;
    float4 v = ((const float4*)src)[i];
    ushort4 o;
    o.x = f2bf(v.x); o.y = f2bf(v.y); o.z = f2bf(v.z); o.w = f2bf(v.w);
    ((ushort4*)dst)[i] = o;
}

// ---------------- fused weight transpose: wq|wk|wv -> wqkvT, wo -> woT ----------------
__global__ void transpose_w(const float* __restrict__ wq, const float* __restrict__ wk,
                            const float* __restrict__ wv, const float* __restrict__ wo,
                            unsigned short* __restrict__ wqkvT, unsigned short* __restrict__ woT) {
    __shared__ float tl[32][33];
    const int tx = threadIdx.x, ty = threadIdx.y;
    const int n0 = blockIdx.x * 32, k0 = blockIdx.y * 32;
    const float* src;
    unsigned short* dstbase;
    int N, nn;
    if (n0 < DIM) { src = wq; N = DIM; nn = n0; dstbase = wqkvT + (size_t)n0 * DIM; }
    else if (n0 < DIM + KVDIM) { src = wk; N = KVDIM; nn = n0 - DIM; dstbase = wqkvT + (size_t)n0 * DIM; }
    else if (n0 < QKVN) { src = wv; N = KVDIM; nn = n0 - DIM - KVDIM; dstbase = wqkvT + (size_t)n0 * DIM; }
    else { src = wo; N = DIM; nn = n0 - QKVN; dstbase = woT + (size_t)(n0 - QKVN) * DIM; }
#pragma unroll
    for (int i = 0; i < 4; ++i)
        tl[ty + i * 8][tx] = src[(size_t)(k0 + ty + i * 8) * N + nn + tx];
    __syncthreads();
#pragma unroll
    for (int i = 0; i < 4; ++i)
        dstbase[(size_t)(ty + i * 8) * DIM + k0 + tx] = f2bf(tl[tx][ty + i * 8]);
}

static __device__ __forceinline__ void store_out(float* p, float v) { *p = v; }
static __device__ __forceinline__ void store_out(unsigned short* p, float v) { *p = f2bf(v); }

// ---------------- 2-phase 128x256 GEMM + fused RoPE/repack epilogue (QKV) ----------------
// R21: BM=128 x BN=256, 384 blocks (1.5 fill-rounds of half-size blocks beats
// 192 blocks at 75% fill). 8 waves = 2M x 4N, AF=4 A-frags x 4 B-frags =
// 16-MFMA clusters (the proven-good size; R10's failure was 8-MFMA clusters).
// Schedule = gemmwo's exact mirror: per stage-call 3 gloads (A=1, B=2);
// steady vmcnt(3) => tile t+1 fully landed; tail vmcnt(0). LDS 96KB.
// B-columns bijectively remapped per-wave (BN=256 unchanged) so the epilogue
// RoPEs in-register and scatters to Qb/Kb/Vt (see R18).
__global__ __launch_bounds__(512, 1) void gemm8_qkv(const unsigned short* __restrict__ A,
                                                    const unsigned short* __restrict__ BT,
                                                    const float2* __restrict__ tab,
                                                    unsigned short* __restrict__ Qb,
                                                    unsigned short* __restrict__ Kb,
                                                    unsigned short* __restrict__ Vt) {
    constexpr int K = DIM, Ntiles = QKVN / 256;  // 12
    __shared__ __align__(16) unsigned short ldsA[2][2][128 * 32];  // 32KB
    __shared__ __align__(16) unsigned short ldsB[2][2][256 * 32];  // 64KB
    const int nwg = gridDim.x;
    const int f = blockIdx.x;
    const int swz = (f & 7) * (nwg >> 3) + (f >> 3);  // nwg % 8 == 0
    const int m0 = (swz / Ntiles) * 128, n0 = (swz % Ntiles) * 256;
    const int t = threadIdx.x;
    const int lane = t & 63, w = t >> 6;
    const int wr = w >> 2, wc = w & 3;
    const int grp = lane >> 4, c = lane & 15;
    const int nkt = K >> 6;
    const int hloc = wc >> 1, qh = wc & 1;

    const int Rs = t >> 2;
    const int cbs = ((t & 3) * 16) ^ ((Rs & 8) << 2);
    const char* Ag = (const char*)A + (size_t)(m0 + Rs) * (K * 2) + cbs;
    const char* Bg = (const char*)BT + (size_t)(n0 + Rs) * (K * 2) + cbs;
    const size_t rowstep = (size_t)128 * K * 2;

    auto stageA = [&](int buf, int ks, int kt) {  // 1 gload (128 rows)
        gload16(Ag + kt * 128 + ks * 64, (char*)&ldsA[buf][ks][0] + t * 16);
    };
    auto stageB = [&](int buf, int ks, int kt) {  // 2 gloads (256 rows)
        const char* g0 = Bg + kt * 128 + ks * 64;
        char* l = (char*)&ldsB[buf][ks][0] + t * 16;
        gload16(g0, l);
        gload16(g0 + rowstep, l + 512 * 16);
    };
    auto rdA = [&](int buf, int ks, int fr) {
        const int R = wr * 64 + fr * 16 + c;
        return *(const bf16x8*)((const char*)&ldsA[buf][ks][0] + R * 64 + ((grp * 16) ^ ((R & 8) << 2)));
    };
    auto rdB = [&](int buf, int ks, int fc) {
        const int R = hloc * 128 + (fc >> 1) * 64 + qh * 32 + (fc & 1) * 16 + c;
        return *(const bf16x8*)((const char*)&ldsB[buf][ks][0] + R * 64 + ((grp * 16) ^ ((R & 8) << 2)));
    };

    f32x4 acc[4][4] = {};
    bf16x8 aF[4], bF0, bF1, bF2, bF3;

    // prologue: tile0 both halves (6 loads) + tile1 ks0 (3 loads)
    stageA(0, 0, 0); stageB(0, 0, 0); stageA(0, 1, 0); stageB(0, 1, 0);
    stageA(1, 0, 1); stageB(1, 0, 1);
    asm volatile("s_waitcnt vmcnt(3)" ::: "memory");  // tile0 fully landed
    asm volatile("s_barrier" ::: "memory");

    for (int kt = 0; kt < nkt; ++kt) {
        const int buf = kt & 1;
        // ---- phase 1: ks0, all 4 B-frags ----
#pragma unroll
        for (int fr = 0; fr < 4; ++fr) aF[fr] = rdA(buf, 0, fr);
        bF0 = rdB(buf, 0, 0); bF1 = rdB(buf, 0, 1); bF2 = rdB(buf, 0, 2); bF3 = rdB(buf, 0, 3);
        if (kt + 1 < nkt) { stageA(buf ^ 1, 1, kt + 1); stageB(buf ^ 1, 1, kt + 1); }
        asm volatile("s_barrier" ::: "memory");
        __builtin_amdgcn_s_setprio(1);
#pragma unroll
        for (int fr = 0; fr < 4; ++fr) {
            acc[fr][0] = __builtin_amdgcn_mfma_f32_16x16x32_bf16(aF[fr], bF0, acc[fr][0], 0, 0, 0);
            acc[fr][1] = __builtin_amdgcn_mfma_f32_16x16x32_bf16(aF[fr], bF1, acc[fr][1], 0, 0, 0);
            acc[fr][2] = __builtin_amdgcn_mfma_f32_16x16x32_bf16(aF[fr], bF2, acc[fr][2], 0, 0, 0);
            acc[fr][3] = __builtin_amdgcn_mfma_f32_16x16x32_bf16(aF[fr], bF3, acc[fr][3], 0, 0, 0);
        }
        __builtin_amdgcn_s_setprio(0);
        asm volatile("s_barrier" ::: "memory");
        // ---- phase 2: ks1, all 4 B-frags ----
#pragma unroll
        for (int fr = 0; fr < 4; ++fr) aF[fr] = rdA(buf, 1, fr);
        bF0 = rdB(buf, 1, 0); bF1 = rdB(buf, 1, 1); bF2 = rdB(buf, 1, 2); bF3 = rdB(buf, 1, 3);
        if (kt + 2 < nkt) { stageA(buf, 0, kt + 2); stageB(buf, 0, kt + 2); }
        asm volatile("s_barrier" ::: "memory");
        __builtin_amdgcn_s_setprio(1);
#pragma unroll
        for (int fr = 0; fr < 4; ++fr) {
            acc[fr][0] = __builtin_amdgcn_mfma_f32_16x16x32_bf16(aF[fr], bF0, acc[fr][0], 0, 0, 0);
            acc[fr][1] = __builtin_amdgcn_mfma_f32_16x16x32_bf16(aF[fr], bF1, acc[fr][1], 0, 0, 0);
            acc[fr][2] = __builtin_amdgcn_mfma_f32_16x16x32_bf16(aF[fr], bF2, acc[fr][2], 0, 0, 0);
            acc[fr][3] = __builtin_amdgcn_mfma_f32_16x16x32_bf16(aF[fr], bF3, acc[fr][3], 0, 0, 0);
        }
        __builtin_amdgcn_s_setprio(0);
        if (kt + 2 < nkt) { asm volatile("s_waitcnt vmcnt(3)" ::: "memory"); }
        else              { asm volatile("s_waitcnt vmcnt(0)" ::: "memory"); }
        asm volatile("s_barrier" ::: "memory");
    }
    // ---- fused epilogue (AF=4 rows: m0 + wr*64 + fr*16 + grp*4 + rr) ----
    const float qscale = 0.08838834764831845f * 1.4426950408889634f;  // 128^-0.5 * log2(e)
    if (n0 < DIM) {                      // Q: RoPE + scale, repack [b,h,t,d]
        const int h = (n0 >> 7) + hloc;
#pragma unroll
        for (int fi = 0; fi < 2; ++fi) {
            const int i = qh * 32 + fi * 16 + c;
#pragma unroll
            for (int fr = 0; fr < 4; ++fr)
#pragma unroll
                for (int rr = 0; rr < 4; ++rr) {
                    const int row = m0 + wr * 64 + fr * 16 + grp * 4 + rr;
                    const int bb = row >> 11, tt = row & 2047;
                    const float2 csn = tab[tt * 64 + i];
                    const float x1 = acc[fr][fi][rr], x2 = acc[fr][2 + fi][rr];
                    unsigned short* dst = Qb + (((size_t)(bb * NH + h)) * T_SEQ + tt) * HD;
                    dst[i] = f2bf((x1 * csn.x - x2 * csn.y) * qscale);
                    dst[i + 64] = f2bf((x2 * csn.x + x1 * csn.y) * qscale);
                }
        }
    } else if (n0 < DIM + KVDIM) {       // K: RoPE, repack [b,g,t,d]
        const int g = ((n0 - DIM) >> 7) + hloc;
#pragma unroll
        for (int fi = 0; fi < 2; ++fi) {
            const int i = qh * 32 + fi * 16 + c;
#pragma unroll
            for (int fr = 0; fr < 4; ++fr)
#pragma unroll
                for (int rr = 0; rr < 4; ++rr) {
                    const int row = m0 + wr * 64 + fr * 16 + grp * 4 + rr;
                    const int bb = row >> 11, tt = row & 2047;
                    const float2 csn = tab[tt * 64 + i];
                    const float x1 = acc[fr][fi][rr], x2 = acc[fr][2 + fi][rr];
                    unsigned short* dst = Kb + (((size_t)(bb * NKV + g)) * T_SEQ + tt) * HD;
                    dst[i] = f2bf(x1 * csn.x - x2 * csn.y);
                    dst[i + 64] = f2bf(x2 * csn.x + x1 * csn.y);
                }
        }
    } else {                             // V: transpose to [b,g,d,t]
        const int g = ((n0 - DIM - KVDIM) >> 7) + hloc;
#pragma unroll
        for (int fc = 0; fc < 4; ++fc) {
            const int d = (fc >> 1) * 64 + qh * 32 + (fc & 1) * 16 + c;
#pragma unroll
            for (int fr = 0; fr < 4; ++fr) {
                const int row0 = m0 + wr * 64 + fr * 16 + grp * 4;
                const int bb = row0 >> 11, tt0 = row0 & 2047;
                unsigned short* dst = Vt + (((size_t)(bb * NKV + g)) * HD + d) * T_SEQ + tt0;
                ushort4 pk;
                pk.x = f2bf(acc[fr][fc][0]); pk.y = f2bf(acc[fr][fc][1]);
                pk.z = f2bf(acc[fr][fc][2]); pk.w = f2bf(acc[fr][fc][3]);
                *(ushort4*)dst = pk;  // tt0 multiple of 4 -> 8B aligned
            }
        }
    }
}

// ---------------- 2-phase 256x128 GEMM for WO (proven R12 config, WO ONLY) ----------------
template <typename OutT>
__global__ __launch_bounds__(512, 1) void gemmwo(const unsigned short* __restrict__ A,
                                                 const unsigned short* __restrict__ BT,
                                                 OutT* __restrict__ C, int M, int N, int K, int Ntiles) {
    __shared__ __align__(16) unsigned short ldsA[2][2][256 * 32];
    __shared__ __align__(16) unsigned short ldsB[2][2][128 * 32];
    const int nwg = gridDim.x;
    const int f = blockIdx.x;
    const int swz = (f & 7) * (nwg >> 3) + (f >> 3);  // nwg % 8 == 0
    const int m0 = (swz / Ntiles) * 256, n0 = (swz % Ntiles) * 128;
    const int t = threadIdx.x;
    const int lane = t & 63, w = t >> 6;
    const int wr = w >> 2, wc = w & 3;
    const int grp = lane >> 4, c = lane & 15;
    const int nkt = K >> 6;

    const int Rs = t >> 2;
    const int cbs = ((t & 3) * 16) ^ ((Rs & 8) << 2);
    const char* Ag = (const char*)A + (size_t)(m0 + Rs) * (K * 2) + cbs;
    const char* Bg = (const char*)BT + (size_t)(n0 + Rs) * (K * 2) + cbs;
    const size_t rowstep = (size_t)128 * K * 2;

    auto stageA = [&](int buf, int ks, int kt) {  // 2 gloads
        const char* g0 = Ag + kt * 128 + ks * 64;
        char* l = (char*)&ldsA[buf][ks][0] + t * 16;
        gload16(g0, l);
        gload16(g0 + rowstep, l + 512 * 16);
    };
    auto stageB = [&](int buf, int ks, int kt) {  // 1 gload (128 rows)
        gload16(Bg + kt * 128 + ks * 64, (char*)&ldsB[buf][ks][0] + t * 16);
    };
    auto rdA = [&](int buf, int ks, int fr) {
        const int R = wr * 128 + fr * 16 + c;
        return *(const bf16x8*)((const char*)&ldsA[buf][ks][0] + R * 64 + ((grp * 16) ^ ((R & 8) << 2)));
    };
    auto rdB = [&](int buf, int ks, int fc) {
        const int R = wc * 32 + fc * 16 + c;
        return *(const bf16x8*)((const char*)&ldsB[buf][ks][0] + R * 64 + ((grp * 16) ^ ((R & 8) << 2)));
    };

    f32x4 acc[8][2] = {};
    bf16x8 aF[8], bF0, bF1;

    stageA(0, 0, 0); stageB(0, 0, 0); stageA(0, 1, 0); stageB(0, 1, 0);
    stageA(1, 0, 1); stageB(1, 0, 1);
    asm volatile("s_waitcnt vmcnt(3)" ::: "memory");  // tile0 landed
    asm volatile("s_barrier" ::: "memory");

    for (int kt = 0; kt < nkt; ++kt) {
        const int buf = kt & 1;
        // ---- phase 1: ks0 ----
#pragma unroll
        for (int fr = 0; fr < 8; ++fr) aF[fr] = rdA(buf, 0, fr);
        bF0 = rdB(buf, 0, 0); bF1 = rdB(buf, 0, 1);
        if (kt + 1 < nkt) { stageA(buf ^ 1, 1, kt + 1); stageB(buf ^ 1, 1, kt + 1); }
        asm volatile("s_barrier" ::: "memory");
        __builtin_amdgcn_s_setprio(1);
#pragma unroll
        for (int fr = 0; fr < 8; ++fr) {
            acc[fr][0] = __builtin_amdgcn_mfma_f32_16x16x32_bf16(aF[fr], bF0, acc[fr][0], 0, 0, 0);
            acc[fr][1] = __builtin_amdgcn_mfma_f32_16x16x32_bf16(aF[fr], bF1, acc[fr][1], 0, 0, 0);
        }
        __builtin_amdgcn_s_setprio(0);
        asm volatile("s_barrier" ::: "memory");
        // ---- phase 2: ks1 ----
#pragma unroll
        for (int fr = 0; fr < 8; ++fr) aF[fr] = rdA(buf, 1, fr);
        bF0 = rdB(buf, 1, 0); bF1 = rdB(buf, 1, 1);
        if (kt + 2 < nkt) { stageA(buf, 0, kt + 2); stageB(buf, 0, kt + 2); }
        asm volatile("s_barrier" ::: "memory");
        __builtin_amdgcn_s_setprio(1);
#pragma unroll
        for (int fr = 0; fr < 8; ++fr) {
            acc[fr][0] = __builtin_amdgcn_mfma_f32_16x16x32_bf16(aF[fr], bF0, acc[fr][0], 0, 0, 0);
            acc[fr][1] = __builtin_amdgcn_mfma_f32_16x16x32_bf16(aF[fr], bF1, acc[fr][1], 0, 0, 0);
        }
        __builtin_amdgcn_s_setprio(0);
        if (kt + 2 < nkt) { asm volatile("s_waitcnt vmcnt(3)" ::: "memory"); }
        else              { asm volatile("s_waitcnt vmcnt(0)" ::: "memory"); }
        asm volatile("s_barrier" ::: "memory");
    }
#pragma unroll
    for (int fr = 0; fr < 8; ++fr)
#pragma unroll
        for (int fc = 0; fc < 2; ++fc)
#pragma unroll
            for (int rr = 0; rr < 4; ++rr) {
                const int row = m0 + wr * 128 + fr * 16 + grp * 4 + rr;
                const int col = n0 + wc * 32 + fc * 16 + c;
                store_out(&C[(size_t)row * N + col], acc[fr][fc][rr]);
            }
}

// ---------------- causal GQA flash attention (R19 version, frozen) ----------------
__global__ __launch_bounds__(512, 4) void attn_kernel(const unsigned short* __restrict__ Qb,
                                                      const unsigned short* __restrict__ Kb,
                                                      const unsigned short* __restrict__ Vt,
                                                      unsigned short* __restrict__ Ob) {
    __shared__ __align__(16) unsigned short Kl[2][KVBLK * HD];  // 2 x 16KB
    __shared__ __align__(16) unsigned short Vl[2][HD * KVBLK];  // 2 x 16KB
    const int bid = blockIdx.x;
    const int bh = bid & 31;
    const int j = bid >> 5;                                    // 0..15
    const int qt = (j < 8) ? (15 - j) : (j - 8);
    const int b = bh >> 4, h = bh & 15;
    const int g = h >> 2;
    const int t = threadIdx.x, lane = t & 63, w = t >> 6;  // w 0..7
    const int grp = lane >> 4, c = lane & 15;
    const int q0 = qt * QBLK;
    const int wq = q0 + w * 16;

    bf16x8 qf[4];
    {
        const size_t qbase = ((size_t)(b * NH + h) * T_SEQ + wq + c) * HD;
#pragma unroll
        for (int kk = 0; kk < 4; ++kk)
            qf[kk] = *(const bf16x8*)(Qb + qbase + kk * 32 + grp * 8);
    }
    const size_t kbase = (size_t)(b * NKV + g) * T_SEQ * HD;

    const char* kp[2];
    const char* vp[2];
#pragma unroll
    for (int i = 0; i < 2; ++i) {
        const int s = (i * 512 + t) * 16;
        const int rl = s >> 8, csw = s & 255;
        const int col = csw ^ ((rl & 15) << 4);                // 16-slot involution
        const int rl32 = rl & 31;
        const int kvrow = (rl >> 5) * 32 + ((rl32 >> 2) & 3) * 8 + ((rl32 >> 4) & 1) * 4 + (rl32 & 3);
        kp[i] = (const char*)(Kb + kbase) + kvrow * (HD * 2) + col;
        const int d = s >> 7, csw2 = s & 127;
        const int kvb = csw2 ^ ((d & 7) << 4);
        vp[i] = (const char*)(Vt + kbase) + (size_t)d * (T_SEQ * 2) + kvb;
    }

    f32x4 o[8] = {};
    float l_run = 0.f;
    const int nkv = (q0 + QBLK) / KVBLK;

#pragma unroll
    for (int i = 0; i < 2; ++i) {
        gload16(kp[i], (char*)Kl[0] + (i * 512 + t) * 16);
        gload16(vp[i], (char*)Vl[0] + (i * 512 + t) * 16);
    }

    for (int kt = 0; kt < nkv; ++kt) {
        const int cur = kt & 1;
        __syncthreads();  // drains vmcnt -> buf[cur] ready; buf[cur^1] free
        if (kt + 1 < nkv) {
#pragma unroll
            for (int i = 0; i < 2; ++i) {
                gload16(kp[i] + (size_t)(kt + 1) * (KVBLK * HD * 2), (char*)Kl[cur ^ 1] + (i * 512 + t) * 16);
                gload16(vp[i] + (size_t)(kt + 1) * (KVBLK * 2), (char*)Vl[cur ^ 1] + (i * 512 + t) * 16);
            }
        }
        const int kv0 = kt * KVBLK;
        if (kv0 > wq + 15) continue;
        // ---- QK^T (swapped: S^T[kv][q]) ----
        f32x4 s4[4] = {};
        __builtin_amdgcn_s_setprio(1);
#pragma unroll
        for (int kvc = 0; kvc < 4; ++kvc) {
            const int row = kvc * 16 + c;
            bf16x8 kf[4];
#pragma unroll
            for (int kk = 0; kk < 4; ++kk)
                kf[kk] = *(const bf16x8*)((const char*)Kl[cur] + row * 256 +
                                          ((kk * 64 + grp * 16) ^ ((row & 15) << 4)));
#pragma unroll
            for (int kk = 0; kk < 4; ++kk)
                s4[kvc] = __builtin_amdgcn_mfma_f32_16x16x32_bf16(kf[kk], qf[kk], s4[kvc], 0, 0, 0);
        }
        __builtin_amdgcn_s_setprio(0);
        // ---- softmax: m=0, per-lane partial l ----
        bf16x8 pb[2];
        if (kv0 + KVBLK - 1 > wq) {  // diagonal tile: causal mask (permuted kv decode)
#pragma unroll
            for (int kvc = 0; kvc < 4; ++kvc)
#pragma unroll
                for (int r = 0; r < 4; ++r) {
                    const int kvg = kv0 + (kvc >> 1) * 32 + grp * 8 + (kvc & 1) * 4 + r;
                    if (kvg > wq + c) s4[kvc][r] = -1e30f;
                }
        }
        float ls = 0.f;
#pragma unroll
        for (int kvc = 0; kvc < 4; ++kvc)
#pragma unroll
            for (int r = 0; r < 4; ++r) {
                const float pv = exp2f(s4[kvc][r]);
                pb[kvc >> 1][(kvc & 1) * 4 + r] = (__bf16)pv;
                ls += pv;
            }
        l_run += ls;
        // ---- PV ----
        __builtin_amdgcn_s_setprio(1);
#pragma unroll
        for (int ch = 0; ch < 2; ++ch) {
#pragma unroll
            for (int dt = 0; dt < 8; ++dt) {
                const int d = dt * 16 + c;
                const bf16x8 vf = *(const bf16x8*)((const char*)Vl[cur] + d * 128 +
                                                   ((ch * 64 + grp * 16) ^ ((d & 7) << 4)));
                o[dt] = __builtin_amdgcn_mfma_f32_16x16x32_bf16(pb[ch], vf, o[dt], 0, 0, 0);
            }
        }
        __builtin_amdgcn_s_setprio(0);
    }
    // ---- epilogue: single cross-lane l reduction ----
    {
        float ls = l_run;
        ls += __shfl_xor(ls, 16);
        ls += __shfl_xor(ls, 32);   // lane l holds l(q = wq + (l&15))
        float lo[4];
#pragma unroll
        for (int r = 0; r < 4; ++r) lo[r] = 1.0f / __shfl(ls, grp * 4 + r);
#pragma unroll
        for (int dt = 0; dt < 8; ++dt)
#pragma unroll
            for (int r = 0; r < 4; ++r) {
                const int trow = wq + grp * 4 + r;
                Ob[((size_t)(b * T_SEQ) + trow) * DIM + h * HD + dt * 16 + c] = f2bf(o[dt][r] * lo[r]);
            }
    }
}

extern "C" void kernel_launch(void* const* d_in, const int* in_sizes, int n_in,
                              void* d_out, int out_size, void* d_ws, size_t ws_size,
                              hipStream_t stream) {
    const float* x = (const float*)d_in[0];
    const float* wq = (const float*)d_in[1];
    const float* wk = (const float*)d_in[2];
    const float* wv = (const float*)d_in[3];
    const float* wo = (const float*)d_in[4];
    float* out = (float*)d_out;

    char* ws = (char*)d_ws;
    size_t off = 0;
    auto alloc = [&](size_t bytes) {
        char* p = ws + off;
        off = (off + bytes + 255) & ~(size_t)255;
        return p;
    };
    unsigned short* xb    = (unsigned short*)alloc((size_t)M_ROWS * DIM * 2);   // later: attnO
    unsigned short* wqkvT = (unsigned short*)alloc((size_t)QKVN * DIM * 2);
    unsigned short* woT   = (unsigned short*)alloc((size_t)DIM * DIM * 2);
    unsigned short* Qb    = (unsigned short*)alloc((size_t)M_ROWS * DIM * 2);
    unsigned short* Kb    = (unsigned short*)alloc((size_t)M_ROWS * KVDIM * 2);
    unsigned short* Vt    = (unsigned short*)alloc((size_t)M_ROWS * KVDIM * 2);
    float2*         tab   = (float2*)alloc((size_t)T_SEQ * 64 * sizeof(float2));
    unsigned short* attnO = xb;  // xb dead after gemm8_qkv

    cvt_f32_bf16<<<(M_ROWS * DIM / 4 + 255) / 256, 256, 0, stream>>>(x, xb, tab, M_ROWS * DIM / 4);

    dim3 tb(32, 8);
    transpose_w<<<dim3((QKVN + DIM) / 32, DIM / 32), tb, 0, stream>>>(wq, wk, wv, wo, wqkvT, woT);

    gemm8_qkv<<<(M_ROWS / 128) * (QKVN / 256), 512, 0, stream>>>(xb, wqkvT, tab, Qb, Kb, Vt);

    attn_kernel<<<(B_SZ * NH) * (T_SEQ / QBLK), 512, 0, stream>>>(Qb, Kb, Vt, attnO);

    gemmwo<float><<<(M_ROWS / 256) * (DIM / 128), 512, 0, stream>>>(attnO, woT, out, M_ROWS, DIM, DIM, DIM / 128);
}

// Round 22
// 186.803 us; speedup vs baseline: 1.1073x; 1.1073x over previous
//
#include <hip/hip_runtime.h>
#include <hip/hip_bf16.h>

#define DIM 2048
#define T_SEQ 2048
#define B_SZ 2
#define NH 16
#define NKV 4
#define HD 128
#define KVDIM (NKV * HD)            // 512
#define M_ROWS (B_SZ * T_SEQ)       // 4096
#define QKVN (DIM + 2 * KVDIM)      // 3072
#define QBLK 128
#define KVBLK 64

typedef float f32x4 __attribute__((ext_vector_type(4)));
typedef __bf16 bf16x8 __attribute__((ext_vector_type(8)));
typedef unsigned short u16x8 __attribute__((ext_vector_type(8)));

static __device__ __forceinline__ float bf2f(unsigned short u) {
    unsigned v = ((unsigned)u) << 16;
    return __builtin_bit_cast(float, v);
}
static __device__ __forceinline__ unsigned short f2bf(float f) {
    __bf16 h = (__bf16)f;
    return __builtin_bit_cast(unsigned short, h);
}

static __device__ __forceinline__ void gload16(const void* g, void* l) {
    __builtin_amdgcn_global_load_lds((const __attribute__((address_space(1))) void*)g,
                                     (__attribute__((address_space(3))) void*)l, 16, 0, 0);
}

// ---------------- elementwise f32 -> bf16, fused RoPE table build ----------------
__global__ void cvt_f32_bf16(const float* __restrict__ src, unsigned short* __restrict__ dst,
                             float2* __restrict__ tab, int n4) {
    int i = blockIdx.x * blockDim.x + threadIdx.x;
    if (blockIdx.x < 512) {  // also build tab[T_SEQ][64] (131072 entries)
        const int idx = blockIdx.x * 256 + threadIdx.x;
        const int tt = idx >> 6, ii = idx & 63;
        const float inv = exp2f(-(float)ii * (13.287712379549449f / 64.0f));  // 10000^(-i/64)
        const float ang = (float)tt * inv;
        tab[idx] = make_float2(cosf(ang), sinf(ang));
    }
    if (i >= n4) return;
    float4 v = ((const float4*)src)[i];
    ushort4 o;
    o.x = f2bf(v.x); o.y = f2bf(v.y); o.z = f2bf(v.z); o.w = f2bf(v.w);
    ((ushort4*)dst)[i] = o;
}

// ---------------- fused weight transpose: wq|wk|wv -> wqkvT, wo -> woT ----------------
__global__ void transpose_w(const float* __restrict__ wq, const float* __restrict__ wk,
                            const float* __restrict__ wv, const float* __restrict__ wo,
                            unsigned short* __restrict__ wqkvT, unsigned short* __restrict__ woT) {
    __shared__ float tl[32][33];
    const int tx = threadIdx.x, ty = threadIdx.y;
    const int n0 = blockIdx.x * 32, k0 = blockIdx.y * 32;
    const float* src;
    unsigned short* dstbase;
    int N, nn;
    if (n0 < DIM) { src = wq; N = DIM; nn = n0; dstbase = wqkvT + (size_t)n0 * DIM; }
    else if (n0 < DIM + KVDIM) { src = wk; N = KVDIM; nn = n0 - DIM; dstbase = wqkvT + (size_t)n0 * DIM; }
    else if (n0 < QKVN) { src = wv; N = KVDIM; nn = n0 - DIM - KVDIM; dstbase = wqkvT + (size_t)n0 * DIM; }
    else { src = wo; N = DIM; nn = n0 - QKVN; dstbase = woT + (size_t)(n0 - QKVN) * DIM; }
#pragma unroll
    for (int i = 0; i < 4; ++i)
        tl[ty + i * 8][tx] = src[(size_t)(k0 + ty + i * 8) * N + nn + tx];
    __syncthreads();
#pragma unroll
    for (int i = 0; i < 4; ++i)
        dstbase[(size_t)(ty + i * 8) * DIM + k0 + tx] = f2bf(tl[tx][ty + i * 8]);
}

static __device__ __forceinline__ void store_out(float* p, float v) { *p = v; }
static __device__ __forceinline__ void store_out(unsigned short* p, float v) { *p = f2bf(v); }

// ---------------- 4-phase 256x256 GEMM + fused RoPE/repack epilogue (QKV) ----------------
// Proven R19 config (71.3 us): gemm8 main loop; B-columns bijectively remapped
// per-wave (wc -> hloc,qh; fc -> p,fi; R = hloc*128 + p*64 + qh*32 + fi*16 + c)
// so the epilogue RoPEs in-register and scatters to Qb/Kb/Vt. Tile-shape search
// exhausted: 256sq/4ph=71.3 > 256sq/2ph=72.4 > 128x256=87.3 (HBM refetch x2).
__global__ __launch_bounds__(512, 2) void gemm8_qkv(const unsigned short* __restrict__ A,
                                                    const unsigned short* __restrict__ BT,
                                                    const float2* __restrict__ tab,
                                                    unsigned short* __restrict__ Qb,
                                                    unsigned short* __restrict__ Kb,
                                                    unsigned short* __restrict__ Vt) {
    constexpr int K = DIM, Ntiles = QKVN / 256;
    __shared__ __align__(16) unsigned short ldsA[2][2][256 * 32];
    __shared__ __align__(16) unsigned short ldsB[2][2][256 * 32];
    const int nwg = gridDim.x;
    const int f = blockIdx.x;
    const int swz = (f & 7) * (nwg >> 3) + (f >> 3);  // nwg % 8 == 0
    const int m0 = (swz / Ntiles) * 256, n0 = (swz % Ntiles) * 256;
    const int t = threadIdx.x;
    const int lane = t & 63, w = t >> 6;
    const int wr = w >> 2, wc = w & 3;
    const int grp = lane >> 4, c = lane & 15;
    const int nkt = K >> 6;
    const int hloc = wc >> 1, qh = wc & 1;

    const int Rs = t >> 2;
    const int cbs = ((t & 3) * 16) ^ ((Rs & 8) << 2);
    const char* Ag = (const char*)A + (size_t)(m0 + Rs) * (K * 2) + cbs;
    const char* Bg = (const char*)BT + (size_t)(n0 + Rs) * (K * 2) + cbs;
    const size_t rowstep = (size_t)128 * K * 2;

    auto stage = [&](int buf, int mat, int ks, int kt) {
        const char* g0 = (mat ? Bg : Ag) + kt * 128 + ks * 64;
        char* l = (mat ? (char*)&ldsB[buf][ks][0] : (char*)&ldsA[buf][ks][0]) + t * 16;
        gload16(g0, l);
        gload16(g0 + rowstep, l + 512 * 16);
    };
    auto rdA = [&](int buf, int ks, int fr) {
        const int R = wr * 128 + fr * 16 + c;
        return *(const bf16x8*)((const char*)&ldsA[buf][ks][0] + R * 64 + ((grp * 16) ^ ((R & 8) << 2)));
    };
    auto rdB = [&](int buf, int ks, int fc) {
        const int R = hloc * 128 + (fc >> 1) * 64 + qh * 32 + (fc & 1) * 16 + c;
        return *(const bf16x8*)((const char*)&ldsB[buf][ks][0] + R * 64 + ((grp * 16) ^ ((R & 8) << 2)));
    };

    f32x4 acc[8][4] = {};
    bf16x8 aF[8], bF0, bF1;

    stage(0, 0, 0, 0); stage(0, 1, 0, 0); stage(0, 0, 1, 0); stage(0, 1, 1, 0);
    stage(1, 0, 0, 1); stage(1, 1, 0, 1);
    asm volatile("s_waitcnt vmcnt(4)" ::: "memory");
    asm volatile("s_barrier" ::: "memory");

    for (int kt = 0; kt < nkt; ++kt) {
        const int buf = kt & 1;
#pragma unroll
        for (int fr = 0; fr < 8; ++fr) aF[fr] = rdA(buf, 0, fr);
        bF0 = rdB(buf, 0, 0); bF1 = rdB(buf, 0, 1);
        if (kt + 1 < nkt) stage(buf ^ 1, 0, 1, kt + 1);
        asm volatile("s_barrier" ::: "memory");
        __builtin_amdgcn_s_setprio(1);
#pragma unroll
        for (int fr = 0; fr < 8; ++fr) {
            acc[fr][0] = __builtin_amdgcn_mfma_f32_16x16x32_bf16(aF[fr], bF0, acc[fr][0], 0, 0, 0);
            acc[fr][1] = __builtin_amdgcn_mfma_f32_16x16x32_bf16(aF[fr], bF1, acc[fr][1], 0, 0, 0);
        }
        __builtin_amdgcn_s_setprio(0);
        asm volatile("s_barrier" ::: "memory");
        bF0 = rdB(buf, 0, 2); bF1 = rdB(buf, 0, 3);
        if (kt + 1 < nkt) stage(buf ^ 1, 1, 1, kt + 1);
        asm volatile("s_barrier" ::: "memory");
        __builtin_amdgcn_s_setprio(1);
#pragma unroll
        for (int fr = 0; fr < 8; ++fr) {
            acc[fr][2] = __builtin_amdgcn_mfma_f32_16x16x32_bf16(aF[fr], bF0, acc[fr][2], 0, 0, 0);
            acc[fr][3] = __builtin_amdgcn_mfma_f32_16x16x32_bf16(aF[fr], bF1, acc[fr][3], 0, 0, 0);
        }
        __builtin_amdgcn_s_setprio(0);
        asm volatile("s_barrier" ::: "memory");
#pragma unroll
        for (int fr = 0; fr < 8; ++fr) aF[fr] = rdA(buf, 1, fr);
        bF0 = rdB(buf, 1, 0); bF1 = rdB(buf, 1, 1);
        if (kt + 2 < nkt) stage(buf, 0, 0, kt + 2);
        asm volatile("s_barrier" ::: "memory");
        __builtin_amdgcn_s_setprio(1);
#pragma unroll
        for (int fr = 0; fr < 8; ++fr) {
            acc[fr][0] = __builtin_amdgcn_mfma_f32_16x16x32_bf16(aF[fr], bF0, acc[fr][0], 0, 0, 0);
            acc[fr][1] = __builtin_amdgcn_mfma_f32_16x16x32_bf16(aF[fr], bF1, acc[fr][1], 0, 0, 0);
        }
        __builtin_amdgcn_s_setprio(0);
        asm volatile("s_barrier" ::: "memory");
        bF0 = rdB(buf, 1, 2); bF1 = rdB(buf, 1, 3);
        if (kt + 2 < nkt) stage(buf, 1, 0, kt + 2);
        asm volatile("s_barrier" ::: "memory");
        __builtin_amdgcn_s_setprio(1);
#pragma unroll
        for (int fr = 0; fr < 8; ++fr) {
            acc[fr][2] = __builtin_amdgcn_mfma_f32_16x16x32_bf16(aF[fr], bF0, acc[fr][2], 0, 0, 0);
            acc[fr][3] = __builtin_amdgcn_mfma_f32_16x16x32_bf16(aF[fr], bF1, acc[fr][3], 0, 0, 0);
        }
        __builtin_amdgcn_s_setprio(0);
        asm volatile("s_waitcnt vmcnt(4)" ::: "memory");
        asm volatile("s_barrier" ::: "memory");
    }
    // ---- fused epilogue ----
    const float qscale = 0.08838834764831845f * 1.4426950408889634f;  // 128^-0.5 * log2(e)
    if (n0 < DIM) {                      // Q: RoPE + scale, repack [b,h,t,d]
        const int h = (n0 >> 7) + hloc;
#pragma unroll
        for (int fi = 0; fi < 2; ++fi) {
            const int i = qh * 32 + fi * 16 + c;
#pragma unroll
            for (int fr = 0; fr < 8; ++fr)
#pragma unroll
                for (int rr = 0; rr < 4; ++rr) {
                    const int row = m0 + wr * 128 + fr * 16 + grp * 4 + rr;
                    const int bb = row >> 11, tt = row & 2047;
                    const float2 csn = tab[tt * 64 + i];
                    const float x1 = acc[fr][fi][rr], x2 = acc[fr][2 + fi][rr];
                    unsigned short* dst = Qb + (((size_t)(bb * NH + h)) * T_SEQ + tt) * HD;
                    dst[i] = f2bf((x1 * csn.x - x2 * csn.y) * qscale);
                    dst[i + 64] = f2bf((x2 * csn.x + x1 * csn.y) * qscale);
                }
        }
    } else if (n0 < DIM + KVDIM) {       // K: RoPE, repack [b,g,t,d]
        const int g = ((n0 - DIM) >> 7) + hloc;
#pragma unroll
        for (int fi = 0; fi < 2; ++fi) {
            const int i = qh * 32 + fi * 16 + c;
#pragma unroll
            for (int fr = 0; fr < 8; ++fr)
#pragma unroll
                for (int rr = 0; rr < 4; ++rr) {
                    const int row = m0 + wr * 128 + fr * 16 + grp * 4 + rr;
                    const int bb = row >> 11, tt = row & 2047;
                    const float2 csn = tab[tt * 64 + i];
                    const float x1 = acc[fr][fi][rr], x2 = acc[fr][2 + fi][rr];
                    unsigned short* dst = Kb + (((size_t)(bb * NKV + g)) * T_SEQ + tt) * HD;
                    dst[i] = f2bf(x1 * csn.x - x2 * csn.y);
                    dst[i + 64] = f2bf(x2 * csn.x + x1 * csn.y);
                }
        }
    } else {                             // V: transpose to [b,g,d,t]
        const int g = ((n0 - DIM - KVDIM) >> 7) + hloc;
#pragma unroll
        for (int fc = 0; fc < 4; ++fc) {
            const int d = (fc >> 1) * 64 + qh * 32 + (fc & 1) * 16 + c;
#pragma unroll
            for (int fr = 0; fr < 8; ++fr) {
                const int row0 = m0 + wr * 128 + fr * 16 + grp * 4;
                const int bb = row0 >> 11, tt0 = row0 & 2047;
                unsigned short* dst = Vt + (((size_t)(bb * NKV + g)) * HD + d) * T_SEQ + tt0;
                ushort4 pk;
                pk.x = f2bf(acc[fr][fc][0]); pk.y = f2bf(acc[fr][fc][1]);
                pk.z = f2bf(acc[fr][fc][2]); pk.w = f2bf(acc[fr][fc][3]);
                *(ushort4*)dst = pk;  // tt0 multiple of 4 -> 8B aligned
            }
        }
    }
}

// ---------------- 2-phase 256x128 GEMM for WO (proven R12 config, WO ONLY) ----------------
template <typename OutT>
__global__ __launch_bounds__(512, 1) void gemmwo(const unsigned short* __restrict__ A,
                                                 const unsigned short* __restrict__ BT,
                                                 OutT* __restrict__ C, int M, int N, int K, int Ntiles) {
    __shared__ __align__(16) unsigned short ldsA[2][2][256 * 32];
    __shared__ __align__(16) unsigned short ldsB[2][2][128 * 32];
    const int nwg = gridDim.x;
    const int f = blockIdx.x;
    const int swz = (f & 7) * (nwg >> 3) + (f >> 3);  // nwg % 8 == 0
    const int m0 = (swz / Ntiles) * 256, n0 = (swz % Ntiles) * 128;
    const int t = threadIdx.x;
    const int lane = t & 63, w = t >> 6;
    const int wr = w >> 2, wc = w & 3;
    const int grp = lane >> 4, c = lane & 15;
    const int nkt = K >> 6;

    const int Rs = t >> 2;
    const int cbs = ((t & 3) * 16) ^ ((Rs & 8) << 2);
    const char* Ag = (const char*)A + (size_t)(m0 + Rs) * (K * 2) + cbs;
    const char* Bg = (const char*)BT + (size_t)(n0 + Rs) * (K * 2) + cbs;
    const size_t rowstep = (size_t)128 * K * 2;

    auto stageA = [&](int buf, int ks, int kt) {  // 2 gloads
        const char* g0 = Ag + kt * 128 + ks * 64;
        char* l = (char*)&ldsA[buf][ks][0] + t * 16;
        gload16(g0, l);
        gload16(g0 + rowstep, l + 512 * 16);
    };
    auto stageB = [&](int buf, int ks, int kt) {  // 1 gload (128 rows)
        gload16(Bg + kt * 128 + ks * 64, (char*)&ldsB[buf][ks][0] + t * 16);
    };
    auto rdA = [&](int buf, int ks, int fr) {
        const int R = wr * 128 + fr * 16 + c;
        return *(const bf16x8*)((const char*)&ldsA[buf][ks][0] + R * 64 + ((grp * 16) ^ ((R & 8) << 2)));
    };
    auto rdB = [&](int buf, int ks, int fc) {
        const int R = wc * 32 + fc * 16 + c;
        return *(const bf16x8*)((const char*)&ldsB[buf][ks][0] + R * 64 + ((grp * 16) ^ ((R & 8) << 2)));
    };

    f32x4 acc[8][2] = {};
    bf16x8 aF[8], bF0, bF1;

    stageA(0, 0, 0); stageB(0, 0, 0); stageA(0, 1, 0); stageB(0, 1, 0);
    stageA(1, 0, 1); stageB(1, 0, 1);
    asm volatile("s_waitcnt vmcnt(3)" ::: "memory");  // tile0 landed
    asm volatile("s_barrier" ::: "memory");

    for (int kt = 0; kt < nkt; ++kt) {
        const int buf = kt & 1;
        // ---- phase 1: ks0 ----
#pragma unroll
        for (int fr = 0; fr < 8; ++fr) aF[fr] = rdA(buf, 0, fr);
        bF0 = rdB(buf, 0, 0); bF1 = rdB(buf, 0, 1);
        if (kt + 1 < nkt) { stageA(buf ^ 1, 1, kt + 1); stageB(buf ^ 1, 1, kt + 1); }
        asm volatile("s_barrier" ::: "memory");
        __builtin_amdgcn_s_setprio(1);
#pragma unroll
        for (int fr = 0; fr < 8; ++fr) {
            acc[fr][0] = __builtin_amdgcn_mfma_f32_16x16x32_bf16(aF[fr], bF0, acc[fr][0], 0, 0, 0);
            acc[fr][1] = __builtin_amdgcn_mfma_f32_16x16x32_bf16(aF[fr], bF1, acc[fr][1], 0, 0, 0);
        }
        __builtin_amdgcn_s_setprio(0);
        asm volatile("s_barrier" ::: "memory");
        // ---- phase 2: ks1 ----
#pragma unroll
        for (int fr = 0; fr < 8; ++fr) aF[fr] = rdA(buf, 1, fr);
        bF0 = rdB(buf, 1, 0); bF1 = rdB(buf, 1, 1);
        if (kt + 2 < nkt) { stageA(buf, 0, kt + 2); stageB(buf, 0, kt + 2); }
        asm volatile("s_barrier" ::: "memory");
        __builtin_amdgcn_s_setprio(1);
#pragma unroll
        for (int fr = 0; fr < 8; ++fr) {
            acc[fr][0] = __builtin_amdgcn_mfma_f32_16x16x32_bf16(aF[fr], bF0, acc[fr][0], 0, 0, 0);
            acc[fr][1] = __builtin_amdgcn_mfma_f32_16x16x32_bf16(aF[fr], bF1, acc[fr][1], 0, 0, 0);
        }
        __builtin_amdgcn_s_setprio(0);
        if (kt + 2 < nkt) { asm volatile("s_waitcnt vmcnt(3)" ::: "memory"); }
        else              { asm volatile("s_waitcnt vmcnt(0)" ::: "memory"); }
        asm volatile("s_barrier" ::: "memory");
    }
#pragma unroll
    for (int fr = 0; fr < 8; ++fr)
#pragma unroll
        for (int fc = 0; fc < 2; ++fc)
#pragma unroll
            for (int rr = 0; rr < 4; ++rr) {
                const int row = m0 + wr * 128 + fr * 16 + grp * 4 + rr;
                const int col = n0 + wc * 32 + fc * 16 + c;
                store_out(&C[(size_t)row * N + col], acc[fr][fc][rr]);
            }
}

// ---------------- causal GQA flash attention (R19 version, frozen) ----------------
__global__ __launch_bounds__(512, 4) void attn_kernel(const unsigned short* __restrict__ Qb,
                                                      const unsigned short* __restrict__ Kb,
                                                      const unsigned short* __restrict__ Vt,
                                                      unsigned short* __restrict__ Ob) {
    __shared__ __align__(16) unsigned short Kl[2][KVBLK * HD];  // 2 x 16KB
    __shared__ __align__(16) unsigned short Vl[2][HD * KVBLK];  // 2 x 16KB
    const int bid = blockIdx.x;
    const int bh = bid & 31;
    const int j = bid >> 5;                                    // 0..15
    const int qt = (j < 8) ? (15 - j) : (j - 8);
    const int b = bh >> 4, h = bh & 15;
    const int g = h >> 2;
    const int t = threadIdx.x, lane = t & 63, w = t >> 6;  // w 0..7
    const int grp = lane >> 4, c = lane & 15;
    const int q0 = qt * QBLK;
    const int wq = q0 + w * 16;

    bf16x8 qf[4];
    {
        const size_t qbase = ((size_t)(b * NH + h) * T_SEQ + wq + c) * HD;
#pragma unroll
        for (int kk = 0; kk < 4; ++kk)
            qf[kk] = *(const bf16x8*)(Qb + qbase + kk * 32 + grp * 8);
    }
    const size_t kbase = (size_t)(b * NKV + g) * T_SEQ * HD;

    const char* kp[2];
    const char* vp[2];
#pragma unroll
    for (int i = 0; i < 2; ++i) {
        const int s = (i * 512 + t) * 16;
        const int rl = s >> 8, csw = s & 255;
        const int col = csw ^ ((rl & 15) << 4);                // 16-slot involution
        const int rl32 = rl & 31;
        const int kvrow = (rl >> 5) * 32 + ((rl32 >> 2) & 3) * 8 + ((rl32 >> 4) & 1) * 4 + (rl32 & 3);
        kp[i] = (const char*)(Kb + kbase) + kvrow * (HD * 2) + col;
        const int d = s >> 7, csw2 = s & 127;
        const int kvb = csw2 ^ ((d & 7) << 4);
        vp[i] = (const char*)(Vt + kbase) + (size_t)d * (T_SEQ * 2) + kvb;
    }

    f32x4 o[8] = {};
    float l_run = 0.f;
    const int nkv = (q0 + QBLK) / KVBLK;

#pragma unroll
    for (int i = 0; i < 2; ++i) {
        gload16(kp[i], (char*)Kl[0] + (i * 512 + t) * 16);
        gload16(vp[i], (char*)Vl[0] + (i * 512 + t) * 16);
    }

    for (int kt = 0; kt < nkv; ++kt) {
        const int cur = kt & 1;
        __syncthreads();  // drains vmcnt -> buf[cur] ready; buf[cur^1] free
        if (kt + 1 < nkv) {
#pragma unroll
            for (int i = 0; i < 2; ++i) {
                gload16(kp[i] + (size_t)(kt + 1) * (KVBLK * HD * 2), (char*)Kl[cur ^ 1] + (i * 512 + t) * 16);
                gload16(vp[i] + (size_t)(kt + 1) * (KVBLK * 2), (char*)Vl[cur ^ 1] + (i * 512 + t) * 16);
            }
        }
        const int kv0 = kt * KVBLK;
        if (kv0 > wq + 15) continue;
        // ---- QK^T (swapped: S^T[kv][q]) ----
        f32x4 s4[4] = {};
        __builtin_amdgcn_s_setprio(1);
#pragma unroll
        for (int kvc = 0; kvc < 4; ++kvc) {
            const int row = kvc * 16 + c;
            bf16x8 kf[4];
#pragma unroll
            for (int kk = 0; kk < 4; ++kk)
                kf[kk] = *(const bf16x8*)((const char*)Kl[cur] + row * 256 +
                                          ((kk * 64 + grp * 16) ^ ((row & 15) << 4)));
#pragma unroll
            for (int kk = 0; kk < 4; ++kk)
                s4[kvc] = __builtin_amdgcn_mfma_f32_16x16x32_bf16(kf[kk], qf[kk], s4[kvc], 0, 0, 0);
        }
        __builtin_amdgcn_s_setprio(0);
        // ---- softmax: m=0, per-lane partial l ----
        bf16x8 pb[2];
        if (kv0 + KVBLK - 1 > wq) {  // diagonal tile: causal mask (permuted kv decode)
#pragma unroll
            for (int kvc = 0; kvc < 4; ++kvc)
#pragma unroll
                for (int r = 0; r < 4; ++r) {
                    const int kvg = kv0 + (kvc >> 1) * 32 + grp * 8 + (kvc & 1) * 4 + r;
                    if (kvg > wq + c) s4[kvc][r] = -1e30f;
                }
        }
        float ls = 0.f;
#pragma unroll
        for (int kvc = 0; kvc < 4; ++kvc)
#pragma unroll
            for (int r = 0; r < 4; ++r) {
                const float pv = exp2f(s4[kvc][r]);
                pb[kvc >> 1][(kvc & 1) * 4 + r] = (__bf16)pv;
                ls += pv;
            }
        l_run += ls;
        // ---- PV ----
        __builtin_amdgcn_s_setprio(1);
#pragma unroll
        for (int ch = 0; ch < 2; ++ch) {
#pragma unroll
            for (int dt = 0; dt < 8; ++dt) {
                const int d = dt * 16 + c;
                const bf16x8 vf = *(const bf16x8*)((const char*)Vl[cur] + d * 128 +
                                                   ((ch * 64 + grp * 16) ^ ((d & 7) << 4)));
                o[dt] = __builtin_amdgcn_mfma_f32_16x16x32_bf16(pb[ch], vf, o[dt], 0, 0, 0);
            }
        }
        __builtin_amdgcn_s_setprio(0);
    }
    // ---- epilogue: single cross-lane l reduction ----
    {
        float ls = l_run;
        ls += __shfl_xor(ls, 16);
        ls += __shfl_xor(ls, 32);   // lane l holds l(q = wq + (l&15))
        float lo[4];
#pragma unroll
        for (int r = 0; r < 4; ++r) lo[r] = 1.0f / __shfl(ls, grp * 4 + r);
#pragma unroll
        for (int dt = 0; dt < 8; ++dt)
#pragma unroll
            for (int r = 0; r < 4; ++r) {
                const int trow = wq + grp * 4 + r;
                Ob[((size_t)(b * T_SEQ) + trow) * DIM + h * HD + dt * 16 + c] = f2bf(o[dt][r] * lo[r]);
            }
    }
}

extern "C" void kernel_launch(void* const* d_in, const int* in_sizes, int n_in,
                              void* d_out, int out_size, void* d_ws, size_t ws_size,
                              hipStream_t stream) {
    const float* x = (const float*)d_in[0];
    const float* wq = (const float*)d_in[1];
    const float* wk = (const float*)d_in[2];
    const float* wv = (const float*)d_in[3];
    const float* wo = (const float*)d_in[4];
    float* out = (float*)d_out;

    char* ws = (char*)d_ws;
    size_t off = 0;
    auto alloc = [&](size_t bytes) {
        char* p = ws + off;
        off = (off + bytes + 255) & ~(size_t)255;
        return p;
    };
    unsigned short* xb    = (unsigned short*)alloc((size_t)M_ROWS * DIM * 2);   // later: attnO
    unsigned short* wqkvT = (unsigned short*)alloc((size_t)QKVN * DIM * 2);
    unsigned short* woT   = (unsigned short*)alloc((size_t)DIM * DIM * 2);
    unsigned short* Qb    = (unsigned short*)alloc((size_t)M_ROWS * DIM * 2);
    unsigned short* Kb    = (unsigned short*)alloc((size_t)M_ROWS * KVDIM * 2);
    unsigned short* Vt    = (unsigned short*)alloc((size_t)M_ROWS * KVDIM * 2);
    float2*         tab   = (float2*)alloc((size_t)T_SEQ * 64 * sizeof(float2));
    unsigned short* attnO = xb;  // xb dead after gemm8_qkv

    cvt_f32_bf16<<<(M_ROWS * DIM / 4 + 255) / 256, 256, 0, stream>>>(x, xb, tab, M_ROWS * DIM / 4);

    dim3 tb(32, 8);
    transpose_w<<<dim3((QKVN + DIM) / 32, DIM / 32), tb, 0, stream>>>(wq, wk, wv, wo, wqkvT, woT);

    gemm8_qkv<<<(M_ROWS / 256) * (QKVN / 256), 512, 0, stream>>>(xb, wqkvT, tab, Qb, Kb, Vt);

    attn_kernel<<<(B_SZ * NH) * (T_SEQ / QBLK), 512, 0, stream>>>(Qb, Kb, Vt, attnO);

    gemmwo<float><<<(M_ROWS / 256) * (DIM / 128), 512, 0, stream>>>(attnO, woT, out, M_ROWS, DIM, DIM, DIM / 128);
}